// Round 8
// baseline (206.641 us; speedup 1.0000x reference)
//
#include <hip/hip_runtime.h>
#include <hip/hip_bf16.h>
#include <math.h>

#define BB 4
#define CC 64
#define HH 128
#define WW 128
#define HW (HH*WW)          // 16384
#define NPIX (BB*HW)        // 65536

typedef __attribute__((ext_vector_type(8))) short short8;   // 8 bf16
typedef __attribute__((ext_vector_type(4))) float f32x4;

__device__ __forceinline__ float bf2f(ushort u) {
  union { unsigned u; float f; } v; v.u = ((unsigned)u) << 16; return v.f;
}
__device__ __forceinline__ ushort f2bf(float f) {
  __hip_bfloat16 h = __float2bfloat16(f); return *(ushort*)&h;
}

// Workspace offsets in ushort units (see plan at bottom).
#define XOFS   0u
#define IOFS   4194304u      // inter_clh
#define ZPOFS  12017664u     // zero page

// ---------------------------------------------------------------------------
// NCHW fp32 -> channels-last bf16 for x and inter (1024 blocks: 512 each).
// ---------------------------------------------------------------------------
__global__ __launch_bounds__(256) void k_transp(
    const float* __restrict__ x, const float* __restrict__ inter,
    ushort* __restrict__ x_clh, ushort* __restrict__ inter_clh) {
  __shared__ float tile[64 * 129];
  int blk = blockIdx.x;
  int sel = blk >> 9;
  int bh = blk & 511;
  int b = bh >> 7, h = bh & 127;
  const float* src = sel ? inter : x;
  ushort* dst = sel ? inter_clh : x_clh;
  const float* sp = src + (size_t)(b * 64) * HW + h * WW;
  for (int i = threadIdx.x; i < 64 * 128; i += 256) {
    int c = i >> 7, w = i & 127;
    tile[c * 129 + w] = sp[(size_t)c * HW + w];
  }
  __syncthreads();
  ushort* dp = dst + ((size_t)b * HW + h * WW) * 64;
  for (int i = threadIdx.x; i < 64 * 128; i += 256) {
    int w = i >> 6, c = i & 63;
    dp[w * 64 + c] = f2bf(tile[c * 129 + w]);
  }
}

// ---------------------------------------------------------------------------
// Weight prep: blk 0..143   -> wfb[tap][m(32)][c(128)] (+ zero page)
//              blk 144..287 -> wdT bf16 [o][k*64+c]
//              blk 288..351 -> SFT weight matrices bf16 [o][c]
// ---------------------------------------------------------------------------
__global__ void k_wprep(const float* __restrict__ w_off,
                        const float* __restrict__ w_dcn,
                        const float* __restrict__ wg1, const float* __restrict__ wb1,
                        const float* __restrict__ wg2, const float* __restrict__ wb2,
                        ushort* __restrict__ wfb, ushort* __restrict__ wdT,
                        ushort* __restrict__ w1gb, ushort* __restrict__ w1bb,
                        ushort* __restrict__ w2gb, ushort* __restrict__ w2bb,
                        float* __restrict__ zp) {
  int blk = blockIdx.x;
  if (blk < 144) {
    int i = blk * 256 + threadIdx.x;
    if (i < 64) zp[i] = 0.f;
    if (i < 9 * 32 * 128) {
      int tap = i >> 12, rem = i & 4095, m = rem >> 7, c = rem & 127;
      float v = (m < 27) ? w_off[(size_t)(m * 128 + c) * 9 + tap] : 0.f;
      wfb[i] = f2bf(v);
    }
  } else if (blk < 288) {
    int i = (blk - 144) * 256 + threadIdx.x;
    if (i < 64 * 64 * 9) {
      int o = i / 576, rem = i % 576, k = rem >> 6, c = rem & 63;
      wdT[i] = f2bf(w_dcn[(o * 64 + c) * 9 + k]);
    }
  } else {
    int i = (blk - 288) * 256 + threadIdx.x;   // 0..16383
    int m = i >> 12, j = i & 4095;
    const float* src = (m == 0) ? wg1 : (m == 1) ? wb1 : (m == 2) ? wg2 : wb2;
    ushort* dst = (m == 0) ? w1gb : (m == 1) ? w1bb : (m == 2) ? w2gb : w2bb;
    dst[j] = f2bf(src[j]);
  }
}

// ---------------------------------------------------------------------------
// Fused SFT on MFMA. Block = 256 thr (4 waves) = 64 px; 1024 blocks.
// ---------------------------------------------------------------------------
#define FPITCH 72   // shorts per px row in Sg/Sb

__global__ __launch_bounds__(256) void k_sft(
    const float* __restrict__ x, const ushort* __restrict__ inter_clh,
    const ushort* __restrict__ w1gb, const ushort* __restrict__ w1bb,
    const ushort* __restrict__ w2gb, const ushort* __restrict__ w2bb,
    float* __restrict__ out) {
  __shared__ ushort Sg[64 * FPITCH];   // 9.2 KB
  __shared__ ushort Sb[64 * FPITCH];   // 9.2 KB
  int tid = threadIdx.x;
  int lane = tid & 63;
  int quad = lane >> 4, col = lane & 15;
  int pg0 = blockIdx.x * 64;
  int b = pg0 >> 14, hw0 = pg0 & 16383;
  int o_base = __builtin_amdgcn_readfirstlane((tid >> 6) * 16);

  // ---- stage A ----
  f32x4 ag[4], ab[4];
#pragma unroll
  for (int nt = 0; nt < 4; ++nt) {
    ag[nt] = (f32x4){0.f, 0.f, 0.f, 0.f};
    ab[nt] = (f32x4){0.f, 0.f, 0.f, 0.f};
  }
#pragma unroll
  for (int ks = 0; ks < 2; ++ks) {
    short8 a_g = *(const short8*)(w1gb + (size_t)(o_base + col) * 64 + ks * 32 + quad * 8);
    short8 a_b = *(const short8*)(w1bb + (size_t)(o_base + col) * 64 + ks * 32 + quad * 8);
#pragma unroll
    for (int nt = 0; nt < 4; ++nt) {
      short8 bf = *(const short8*)(inter_clh + (size_t)(pg0 + nt * 16 + col) * 64 + ks * 32 + quad * 8);
      ag[nt] = __builtin_amdgcn_mfma_f32_16x16x32_bf16(a_g, bf, ag[nt], 0, 0, 0);
      ab[nt] = __builtin_amdgcn_mfma_f32_16x16x32_bf16(a_b, bf, ab[nt], 0, 0, 0);
    }
  }
  // lrelu + D-layout -> LDS [px][o]
#pragma unroll
  for (int nt = 0; nt < 4; ++nt) {
    int px = nt * 16 + col;
    ushort pkg[4], pkb[4];
#pragma unroll
    for (int r = 0; r < 4; ++r) {
      float vg = ag[nt][r]; vg = vg >= 0.f ? vg : 0.1f * vg;
      float vb = ab[nt][r]; vb = vb >= 0.f ? vb : 0.1f * vb;
      pkg[r] = f2bf(vg); pkb[r] = f2bf(vb);
    }
    *(uint2*)(&Sg[px * FPITCH + o_base + quad * 4]) = *(uint2*)pkg;
    *(uint2*)(&Sb[px * FPITCH + o_base + quad * 4]) = *(uint2*)pkb;
  }
  __syncthreads();

  // ---- stage B ----
  f32x4 gg[4], gb[4];
#pragma unroll
  for (int nt = 0; nt < 4; ++nt) {
    gg[nt] = (f32x4){0.f, 0.f, 0.f, 0.f};
    gb[nt] = (f32x4){0.f, 0.f, 0.f, 0.f};
  }
#pragma unroll
  for (int ks = 0; ks < 2; ++ks) {
    short8 a_g = *(const short8*)(w2gb + (size_t)(o_base + col) * 64 + ks * 32 + quad * 8);
    short8 a_b = *(const short8*)(w2bb + (size_t)(o_base + col) * 64 + ks * 32 + quad * 8);
#pragma unroll
    for (int nt = 0; nt < 4; ++nt) {
      short8 bg = *(const short8*)(Sg + (nt * 16 + col) * FPITCH + ks * 32 + quad * 8);
      short8 bb = *(const short8*)(Sb + (nt * 16 + col) * FPITCH + ks * 32 + quad * 8);
      gg[nt] = __builtin_amdgcn_mfma_f32_16x16x32_bf16(a_g, bg, gg[nt], 0, 0, 0);
      gb[nt] = __builtin_amdgcn_mfma_f32_16x16x32_bf16(a_b, bb, gb[nt], 0, 0, 0);
    }
  }

  // ---- epilogue: out = x*(1+gamma) + beta ----
#pragma unroll
  for (int nt = 0; nt < 4; ++nt) {
#pragma unroll
    for (int r = 0; r < 4; ++r) {
      int o = o_base + quad * 4 + r;
      size_t idx = (size_t)(b * 64 + o) * HW + hw0 + nt * 16 + col;
      float xv = x[idx];
      out[idx] = xv + xv * gg[nt][r] + gb[nt][r];
    }
  }
}

// ---------------------------------------------------------------------------
// Offset conv v3: high-TLP + explicit depth-1 tap pipeline.
// Grid 2048 (b x h x w-quarter), block = 4 waves: wave = (pt, mt), 16px x
// 16out each. Per tap: 4 B-loads (x/inter, 2 ksteps) + 4 A-loads; the NEXT
// tap's 8 loads are issued in program order BEFORE this tap's MFMAs, so the
// compiler's waitcnt is vmcnt(8)-style, not a full drain (v2 serialized one
// L2 round trip per load: VGPR=104, 36 round trips/iter). Border taps point
// both sources at the real zero page (fixes v2's zp+IOFS poison read).
// ---------------------------------------------------------------------------
__global__ __launch_bounds__(256, 4) void k_convm(
    const ushort* __restrict__ wsb, const ushort* __restrict__ wfb,
    float* __restrict__ om) {
  int tid = threadIdx.x;
  int wave = tid >> 6, lane = tid & 63;
  int quad = lane >> 4, col = lane & 15;
  int blk = blockIdx.x;                 // b(4) x h(128) x wq(4)
  int b = blk >> 9, h = (blk >> 2) & 127, wq = blk & 3;
  int pt = wave >> 1, mt = wave & 1;
  int px = wq * 32 + pt * 16 + col;

  unsigned bslab = (unsigned)b * HW * 64;
  unsigned ofsx[9], ofsi[9];
#pragma unroll
  for (int ky = 0; ky < 3; ++ky) {
    int hs = h + ky - 1;
    bool hok = (unsigned)hs < 128u;
#pragma unroll
    for (int kx = 0; kx < 3; ++kx) {
      int ps = px + kx - 1;
      bool ok = hok && ((unsigned)ps < 128u);
      unsigned o = bslab + (unsigned)((hs << 7) + ps) * 64 + quad * 8;
      ofsx[ky * 3 + kx] = ok ? (XOFS + o) : ZPOFS;
      ofsi[ky * 3 + kx] = ok ? (IOFS + o) : ZPOFS;
    }
  }

  const ushort* wb0 = wfb + (size_t)(mt * 16 + col) * 128 + quad * 8;

  short8 bx0[2], bx1[2], bi0[2], bi1[2], a0[2], a1[2], a2[2], a3[2];
  {   // prologue: tap 0
    const ushort* pxp = wsb + ofsx[0];
    const ushort* pip = wsb + ofsi[0];
    bx0[0] = *(const short8*)(pxp);
    bx1[0] = *(const short8*)(pxp + 32);
    bi0[0] = *(const short8*)(pip);
    bi1[0] = *(const short8*)(pip + 32);
    a0[0] = *(const short8*)(wb0 + 0);
    a1[0] = *(const short8*)(wb0 + 32);
    a2[0] = *(const short8*)(wb0 + 64);
    a3[0] = *(const short8*)(wb0 + 96);
  }

  f32x4 accx = {0.f, 0.f, 0.f, 0.f}, acci = {0.f, 0.f, 0.f, 0.f};
#pragma unroll
  for (int tap = 0; tap < 9; ++tap) {
    int cur = tap & 1, nxt = cur ^ 1;
    if (tap < 8) {   // prefetch tap+1 (issues before cur's waitcnt)
      const ushort* pxp = wsb + ofsx[tap + 1];
      const ushort* pip = wsb + ofsi[tap + 1];
      bx0[nxt] = *(const short8*)(pxp);
      bx1[nxt] = *(const short8*)(pxp + 32);
      bi0[nxt] = *(const short8*)(pip);
      bi1[nxt] = *(const short8*)(pip + 32);
      const ushort* wt = wb0 + (size_t)(tap + 1) * 4096;
      a0[nxt] = *(const short8*)(wt + 0);
      a1[nxt] = *(const short8*)(wt + 32);
      a2[nxt] = *(const short8*)(wt + 64);
      a3[nxt] = *(const short8*)(wt + 96);
    }
    accx = __builtin_amdgcn_mfma_f32_16x16x32_bf16(a0[cur], bx0[cur], accx, 0, 0, 0);
    accx = __builtin_amdgcn_mfma_f32_16x16x32_bf16(a1[cur], bx1[cur], accx, 0, 0, 0);
    acci = __builtin_amdgcn_mfma_f32_16x16x32_bf16(a2[cur], bi0[cur], acci, 0, 0, 0);
    acci = __builtin_amdgcn_mfma_f32_16x16x32_bf16(a3[cur], bi1[cur], acci, 0, 0, 0);
  }

  int pg = b * HW + h * WW + px;
#pragma unroll
  for (int r = 0; r < 4; ++r) {
    int o = mt * 16 + quad * 4 + r;
    float v = accx[r] + acci[r];
    if (o < 27) om[(size_t)o * NPIX + pg] = v;
  }
}

// ---------------------------------------------------------------------------
// DCN v3. Block = 256 thr (4 waves) = 32 pixels; 2048 blocks (8/CU).
// ---------------------------------------------------------------------------
#define SPITCH 200   // shorts per pixel row (192 + 8 pad)
#define NPX 32       // pixels per block

__global__ __launch_bounds__(256) void k_dcn(
    const ushort* __restrict__ x_clh, const float* __restrict__ om,
    const float* __restrict__ b_off, const ushort* __restrict__ wdT,
    const ushort* __restrict__ zp16,
    float* __restrict__ out) {
  __shared__ ushort S[NPX * SPITCH];       // 12.8 KB
  __shared__ int   cy[9 * NPX], cx[9 * NPX];
  __shared__ float cwy[9 * NPX], cwx[9 * NPX], cm[9 * NPX];

  int tid = threadIdx.x;
  int wave = tid >> 6, lane = tid & 63;
  int quad = lane >> 4, col = lane & 15;
  int rr = lane >> 3, g = lane & 7;        // gather: row-in-group, ch-group
  int pg0 = blockIdx.x * NPX;
  int b = pg0 >> 14;
  int o_base = __builtin_amdgcn_readfirstlane(wave * 16);

  // ---- phase 0: coords once per (pixel, tap), lane = pixel ----
  for (int i = tid; i < 9 * NPX; i += 256) {
    int k = i >> 5, p = i & 31;
    int pg = pg0 + p;
    int hw = pg & 16383;
    int h = hw >> 7, w = hw & 127;
    float dy = om[(size_t)k * NPIX + pg] + b_off[k];
    float dx = om[(size_t)(9 + k) * NPIX + pg] + b_off[9 + k];
    float mz = om[(size_t)(18 + k) * NPIX + pg] + b_off[18 + k];
    float py = (float)(h + (k / 3) - 1) + dy;
    float px = (float)(w + (k % 3) - 1) + dx;
    float y0f = floorf(py), x0f = floorf(px);
    cy[i] = (int)y0f;
    cx[i] = (int)x0f;
    cwy[i] = py - y0f;
    cwx[i] = px - x0f;
    cm[i] = 1.f / (1.f + __expf(-mz));
  }

  f32x4 acc[2];
  acc[0] = (f32x4){0.f, 0.f, 0.f, 0.f};
  acc[1] = (f32x4){0.f, 0.f, 0.f, 0.f};

  const ushort* bp = x_clh + (size_t)b * HW * 64;

  for (int chunk = 0; chunk < 3; ++chunk) {
    __syncthreads();   // chunk 0: coords ready; later: S free for reuse
    // ---- phase 1: 96 rows; iteration `it` covers tap kk=it, px p=wave*8+rr
#pragma unroll
    for (int it = 0; it < 3; ++it) {
      int p = wave * 8 + rr;
      int idx = (chunk * 3 + it) * NPX + p;
      int y0 = cy[idx], x0 = cx[idx];
      float wy = cwy[idx], wx = cwx[idx], m = cm[idx];
      bool yok0 = (unsigned)y0 < 128u, yok1 = (unsigned)(y0 + 1) < 128u;
      bool xok0 = (unsigned)x0 < 128u, xok1 = (unsigned)(x0 + 1) < 128u;
      const ushort* r0 = bp + ((size_t)(int)((y0 << 7) + x0)) * 64 + g * 8;
      const ushort* r1 = r0 + (size_t)WW * 64;
      short8 s00 = *(const short8*)((yok0 && xok0) ? r0 : zp16);
      short8 s01 = *(const short8*)((yok0 && xok1) ? (r0 + 64) : zp16);
      short8 s10 = *(const short8*)((yok1 && xok0) ? r1 : zp16);
      short8 s11 = *(const short8*)((yok1 && xok1) ? (r1 + 64) : zp16);
      short8 outv;
#pragma unroll
      for (int j = 0; j < 8; ++j) {
        float v00 = bf2f((ushort)s00[j]), v01 = bf2f((ushort)s01[j]);
        float v10 = bf2f((ushort)s10[j]), v11 = bf2f((ushort)s11[j]);
        float top = v00 + (v01 - v00) * wx;
        float bot = v10 + (v11 - v10) * wx;
        float val = top + (bot - top) * wy;
        outv[j] = (short)f2bf(val * m);
      }
      *(short8*)(&S[p * SPITCH + it * 64 + g * 8]) = outv;
    }
    __syncthreads();
    // ---- phase 2: MFMA over this chunk's K=192 ----
    const ushort* wrow = wdT + (size_t)(o_base + col) * 576 + chunk * 192 + quad * 8;
    const ushort* srow = S + quad * 8;
#pragma unroll
    for (int ks = 0; ks < 6; ++ks) {
      short8 a = *(const short8*)(wrow + ks * 32);
#pragma unroll
      for (int nt = 0; nt < 2; ++nt) {
        short8 bf = *(const short8*)(srow + (nt * 16 + col) * SPITCH + ks * 32);
        acc[nt] = __builtin_amdgcn_mfma_f32_16x16x32_bf16(a, bf, acc[nt], 0, 0, 0);
      }
    }
  }

  // ---- epilogue: out[(b*64+o)*HW + hw0 + px] += D ----
  int hw0 = pg0 & 16383;
#pragma unroll
  for (int nt = 0; nt < 2; ++nt) {
#pragma unroll
    for (int r = 0; r < 4; ++r) {
      int o = o_base + quad * 4 + r;
      size_t idx = (size_t)(b * 64 + o) * HW + hw0 + nt * 16 + col;
      out[idx] += acc[nt][r];
    }
  }
}

// ---------------------------------------------------------------------------
// Workspace plan (float slots), all concurrent (~24 MB):
//   x_clh     ushort [0        .. 2097152)   ushort-ofs 0        (XOFS)
//   inter_clh ushort [2097152  .. 4194304)   ushort-ofs 4194304  (IOFS)
//   om        fp32   [4194304  .. 5963776)
//   wfb       ushort [5963776  .. 5982208)
//   wdT       ushort [5982208  .. 6000640)
//   w1gb/w1bb/w2gb/w2bb ushort 4 x 2048 float slots [6000640 .. 6008832)
//   zp        fp32   [6008832  .. 6008896)   ushort-ofs 12017664 (ZPOFS)
// ---------------------------------------------------------------------------
extern "C" void kernel_launch(void* const* d_in, const int* in_sizes, int n_in,
                              void* d_out, int out_size, void* d_ws, size_t ws_size,
                              hipStream_t stream) {
  const float* x     = (const float*)d_in[0];
  const float* inter = (const float*)d_in[1];
  const float* w_off = (const float*)d_in[2];
  const float* b_off = (const float*)d_in[3];
  const float* w_dcn = (const float*)d_in[4];
  const float* wg1   = (const float*)d_in[5];
  const float* wg2   = (const float*)d_in[6];
  const float* wb1   = (const float*)d_in[7];
  const float* wb2   = (const float*)d_in[8];
  float* out = (float*)d_out;

  float* ws        = (float*)d_ws;
  ushort* wsb      = (ushort*)d_ws;
  ushort* x_clh    = (ushort*)ws;
  ushort* inter_clh= (ushort*)(ws + 2097152);
  float* om        = ws + 4194304;
  ushort* wfb      = (ushort*)(ws + 5963776);
  ushort* wdT      = (ushort*)(ws + 5982208);
  ushort* w1gb     = (ushort*)(ws + 6000640);
  ushort* w1bb     = (ushort*)(ws + 6002688);
  ushort* w2gb     = (ushort*)(ws + 6004736);
  ushort* w2bb     = (ushort*)(ws + 6006784);
  float* zp        = ws + 6008832;

  // Prep: channels-last bf16 inputs + all packed weights + zero page.
  k_transp<<<1024, 256, 0, stream>>>(x, inter, x_clh, inter_clh);
  k_wprep<<<352, 256, 0, stream>>>(w_off, w_dcn, wg1, wb1, wg2, wb2,
                                   wfb, wdT, w1gb, w1bb, w2gb, w2bb, zp);

  // SFT (MFMA, fused two stages): out = x*(1+gamma)+beta.
  k_sft<<<1024, 256, 0, stream>>>(x, inter_clh, w1gb, w1bb, w2gb, w2bb, out);

  // Offset conv (pipelined MFMA implicit GEMM, 2048 blocks).
  k_convm<<<2048, 256, 0, stream>>>(wsb, wfb, om);

  // DCN (adds into out).
  k_dcn<<<2048, 256, 0, stream>>>(x_clh, om, b_off, wdT, (const ushort*)zp, out);
}

// Round 9
// 181.143 us; speedup vs baseline: 1.1408x; 1.1408x over previous
//
#include <hip/hip_runtime.h>
#include <hip/hip_bf16.h>
#include <math.h>

#define BB 4
#define CC 64
#define HH 128
#define WW 128
#define HW (HH*WW)          // 16384
#define NPIX (BB*HW)        // 65536

typedef __attribute__((ext_vector_type(8))) short short8;   // 8 bf16
typedef __attribute__((ext_vector_type(4))) float f32x4;

__device__ __forceinline__ float bf2f(ushort u) {
  union { unsigned u; float f; } v; v.u = ((unsigned)u) << 16; return v.f;
}
__device__ __forceinline__ ushort f2bf(float f) {
  __hip_bfloat16 h = __float2bfloat16(f); return *(ushort*)&h;
}

// ---------------------------------------------------------------------------
// NCHW fp32 -> channels-last bf16 for x and inter (1024 blocks: 512 each).
// ---------------------------------------------------------------------------
__global__ __launch_bounds__(256) void k_transp(
    const float* __restrict__ x, const float* __restrict__ inter,
    ushort* __restrict__ x_clh, ushort* __restrict__ inter_clh) {
  __shared__ float tile[64 * 129];
  int blk = blockIdx.x;
  int sel = blk >> 9;
  int bh = blk & 511;
  int b = bh >> 7, h = bh & 127;
  const float* src = sel ? inter : x;
  ushort* dst = sel ? inter_clh : x_clh;
  const float* sp = src + (size_t)(b * 64) * HW + h * WW;
  for (int i = threadIdx.x; i < 64 * 128; i += 256) {
    int c = i >> 7, w = i & 127;
    tile[c * 129 + w] = sp[(size_t)c * HW + w];
  }
  __syncthreads();
  ushort* dp = dst + ((size_t)b * HW + h * WW) * 64;
  for (int i = threadIdx.x; i < 64 * 128; i += 256) {
    int w = i >> 6, c = i & 63;
    dp[w * 64 + c] = f2bf(tile[c * 129 + w]);
  }
}

// ---------------------------------------------------------------------------
// Weight prep: blk 0..143   -> wfb[tap][m(32)][c(128)] (+ zero page)
//              blk 144..287 -> wdT bf16 [o][k*64+c]
//              blk 288..351 -> SFT weight matrices bf16 [o][c]
// ---------------------------------------------------------------------------
__global__ void k_wprep(const float* __restrict__ w_off,
                        const float* __restrict__ w_dcn,
                        const float* __restrict__ wg1, const float* __restrict__ wb1,
                        const float* __restrict__ wg2, const float* __restrict__ wb2,
                        ushort* __restrict__ wfb, ushort* __restrict__ wdT,
                        ushort* __restrict__ w1gb, ushort* __restrict__ w1bb,
                        ushort* __restrict__ w2gb, ushort* __restrict__ w2bb,
                        float* __restrict__ zp) {
  int blk = blockIdx.x;
  if (blk < 144) {
    int i = blk * 256 + threadIdx.x;
    if (i < 64) zp[i] = 0.f;
    if (i < 9 * 32 * 128) {
      int tap = i >> 12, rem = i & 4095, m = rem >> 7, c = rem & 127;
      float v = (m < 27) ? w_off[(size_t)(m * 128 + c) * 9 + tap] : 0.f;
      wfb[i] = f2bf(v);
    }
  } else if (blk < 288) {
    int i = (blk - 144) * 256 + threadIdx.x;
    if (i < 64 * 64 * 9) {
      int o = i / 576, rem = i % 576, k = rem >> 6, c = rem & 63;
      wdT[i] = f2bf(w_dcn[(o * 64 + c) * 9 + k]);
    }
  } else {
    int i = (blk - 288) * 256 + threadIdx.x;   // 0..16383
    int m = i >> 12, j = i & 4095;
    const float* src = (m == 0) ? wg1 : (m == 1) ? wb1 : (m == 2) ? wg2 : wb2;
    ushort* dst = (m == 0) ? w1gb : (m == 1) ? w1bb : (m == 2) ? w2gb : w2bb;
    dst[j] = f2bf(src[j]);
  }
}

// ---------------------------------------------------------------------------
// Fused SFT on MFMA. Block = 256 thr (4 waves) = 64 px; 1024 blocks.
// ---------------------------------------------------------------------------
#define FPITCH 72   // shorts per px row in Sg/Sb

__global__ __launch_bounds__(256) void k_sft(
    const float* __restrict__ x, const ushort* __restrict__ inter_clh,
    const ushort* __restrict__ w1gb, const ushort* __restrict__ w1bb,
    const ushort* __restrict__ w2gb, const ushort* __restrict__ w2bb,
    float* __restrict__ out) {
  __shared__ ushort Sg[64 * FPITCH];   // 9.2 KB
  __shared__ ushort Sb[64 * FPITCH];   // 9.2 KB
  int tid = threadIdx.x;
  int lane = tid & 63;
  int quad = lane >> 4, col = lane & 15;
  int pg0 = blockIdx.x * 64;
  int b = pg0 >> 14, hw0 = pg0 & 16383;
  int o_base = __builtin_amdgcn_readfirstlane((tid >> 6) * 16);

  // ---- stage A ----
  f32x4 ag[4], ab[4];
#pragma unroll
  for (int nt = 0; nt < 4; ++nt) {
    ag[nt] = (f32x4){0.f, 0.f, 0.f, 0.f};
    ab[nt] = (f32x4){0.f, 0.f, 0.f, 0.f};
  }
#pragma unroll
  for (int ks = 0; ks < 2; ++ks) {
    short8 a_g = *(const short8*)(w1gb + (size_t)(o_base + col) * 64 + ks * 32 + quad * 8);
    short8 a_b = *(const short8*)(w1bb + (size_t)(o_base + col) * 64 + ks * 32 + quad * 8);
#pragma unroll
    for (int nt = 0; nt < 4; ++nt) {
      short8 bf = *(const short8*)(inter_clh + (size_t)(pg0 + nt * 16 + col) * 64 + ks * 32 + quad * 8);
      ag[nt] = __builtin_amdgcn_mfma_f32_16x16x32_bf16(a_g, bf, ag[nt], 0, 0, 0);
      ab[nt] = __builtin_amdgcn_mfma_f32_16x16x32_bf16(a_b, bf, ab[nt], 0, 0, 0);
    }
  }
  // lrelu + D-layout -> LDS [px][o]
#pragma unroll
  for (int nt = 0; nt < 4; ++nt) {
    int px = nt * 16 + col;
    ushort pkg[4], pkb[4];
#pragma unroll
    for (int r = 0; r < 4; ++r) {
      float vg = ag[nt][r]; vg = vg >= 0.f ? vg : 0.1f * vg;
      float vb = ab[nt][r]; vb = vb >= 0.f ? vb : 0.1f * vb;
      pkg[r] = f2bf(vg); pkb[r] = f2bf(vb);
    }
    *(uint2*)(&Sg[px * FPITCH + o_base + quad * 4]) = *(uint2*)pkg;
    *(uint2*)(&Sb[px * FPITCH + o_base + quad * 4]) = *(uint2*)pkb;
  }
  __syncthreads();

  // ---- stage B ----
  f32x4 gg[4], gb[4];
#pragma unroll
  for (int nt = 0; nt < 4; ++nt) {
    gg[nt] = (f32x4){0.f, 0.f, 0.f, 0.f};
    gb[nt] = (f32x4){0.f, 0.f, 0.f, 0.f};
  }
#pragma unroll
  for (int ks = 0; ks < 2; ++ks) {
    short8 a_g = *(const short8*)(w2gb + (size_t)(o_base + col) * 64 + ks * 32 + quad * 8);
    short8 a_b = *(const short8*)(w2bb + (size_t)(o_base + col) * 64 + ks * 32 + quad * 8);
#pragma unroll
    for (int nt = 0; nt < 4; ++nt) {
      short8 bg = *(const short8*)(Sg + (nt * 16 + col) * FPITCH + ks * 32 + quad * 8);
      short8 bb = *(const short8*)(Sb + (nt * 16 + col) * FPITCH + ks * 32 + quad * 8);
      gg[nt] = __builtin_amdgcn_mfma_f32_16x16x32_bf16(a_g, bg, gg[nt], 0, 0, 0);
      gb[nt] = __builtin_amdgcn_mfma_f32_16x16x32_bf16(a_b, bb, gb[nt], 0, 0, 0);
    }
  }

  // ---- epilogue: out = x*(1+gamma) + beta ----
#pragma unroll
  for (int nt = 0; nt < 4; ++nt) {
#pragma unroll
    for (int r = 0; r < 4; ++r) {
      int o = o_base + quad * 4 + r;
      size_t idx = (size_t)(b * 64 + o) * HW + hw0 + nt * 16 + col;
      float xv = x[idx];
      out[idx] = xv + xv * gg[nt][r] + gb[nt][r];
    }
  }
}

// ---------------------------------------------------------------------------
// Offset conv v4: LDS-staged implicit GEMM (the structure this compiler
// schedules well; R6-R8 global->MFMA variants all serialized: VGPR 40/104/
// 36-with-spills). Grid 2048 = (b, h, wq); block = 256 thr = 32 px.
// LDS tile: [src(2) x row(3)][px 34][ch 64] bf16, ch-pitch 72 shorts ->
//   col stride 36 dwords (2-way bank aliasing = free), staging writes at the
//   8/bank floor. 29.4 KB -> 5 blocks/CU = 20 waves/CU.
// Staging: 7 coalesced iterations, 8 lanes = one pixel's 64 ch (128 B),
//   borders zero-selected. Compute: wave = (pt, mt) 16px x 16out; per
//   tap/src/ks: global A-load (wfb, L2-hot) + ds_read_b128 B + MFMA.
// ---------------------------------------------------------------------------
#define CPITCH 72   // shorts per (srcrow, px) channel row

__global__ __launch_bounds__(256) void k_convm(
    const ushort* __restrict__ x_clh, const ushort* __restrict__ inter_clh,
    const ushort* __restrict__ wfb, float* __restrict__ om) {
  __shared__ ushort S[6 * 34 * CPITCH];   // 29376 B
  int tid = threadIdx.x;
  int wave = tid >> 6, lane = tid & 63;
  int quad = lane >> 4, col = lane & 15;
  int blk = blockIdx.x;                 // b(4) x h(128) x wq(4)
  int b = blk >> 9, h = (blk >> 2) & 127, wq = blk & 3;
  int pt = wave >> 1, mt = wave & 1;

  // ---- staging: 204 entries (srcrow 0..5, pxl 0..33), 8 lanes/entry ----
  {
    int ch = (tid & 7) * 8;
    unsigned bbase = (unsigned)b * HW;
#pragma unroll
    for (int it = 0; it < 7; ++it) {
      int e = it * 32 + (tid >> 3);
      if (e < 204) {
        int srcrow = e / 34, pxl = e % 34;
        int src = srcrow / 3, row = srcrow % 3;
        int hs = h + row - 1;
        int ps = wq * 32 + pxl - 1;
        bool ok = ((unsigned)hs < 128u) && ((unsigned)ps < 128u);
        int hc = hs < 0 ? 0 : (hs > 127 ? 127 : hs);
        int pc = ps < 0 ? 0 : (ps > 127 ? 127 : ps);
        const ushort* sb = src ? inter_clh : x_clh;
        short8 v = *(const short8*)(sb + ((size_t)(bbase + (hc << 7) + pc)) * 64 + ch);
        short8 z = {0, 0, 0, 0, 0, 0, 0, 0};
        if (!ok) v = z;
        *(short8*)(&S[e * CPITCH + ch]) = v;
      }
    }
  }
  __syncthreads();

  // ---- compute: wave (pt, mt): 16 px x 16 out ----
  f32x4 accx = {0.f, 0.f, 0.f, 0.f}, acci = {0.f, 0.f, 0.f, 0.f};
  const ushort* wb0 = wfb + (size_t)(mt * 16 + col) * 128 + quad * 8;
  int pxb = pt * 16 + col;

#pragma unroll
  for (int ky = 0; ky < 3; ++ky) {
#pragma unroll
    for (int kx = 0; kx < 3; ++kx) {
      int tap = ky * 3 + kx;
      const ushort* wt = wb0 + (size_t)tap * 4096;
#pragma unroll
      for (int ks = 0; ks < 2; ++ks) {
        // src 0 (x)
        short8 a0 = *(const short8*)(wt + ks * 32);
        short8 b0 = *(const short8*)(&S[(ky * 34 + pxb + kx) * CPITCH + ks * 32 + quad * 8]);
        accx = __builtin_amdgcn_mfma_f32_16x16x32_bf16(a0, b0, accx, 0, 0, 0);
        // src 1 (inter)
        short8 a1 = *(const short8*)(wt + 64 + ks * 32);
        short8 b1 = *(const short8*)(&S[((3 + ky) * 34 + pxb + kx) * CPITCH + ks * 32 + quad * 8]);
        acci = __builtin_amdgcn_mfma_f32_16x16x32_bf16(a1, b1, acci, 0, 0, 0);
      }
    }
  }

  int pg = b * HW + h * WW + wq * 32 + pt * 16 + col;
#pragma unroll
  for (int r = 0; r < 4; ++r) {
    int o = mt * 16 + quad * 4 + r;
    float v = accx[r] + acci[r];
    if (o < 27) om[(size_t)o * NPIX + pg] = v;
  }
}

// ---------------------------------------------------------------------------
// DCN v3. Block = 256 thr (4 waves) = 32 pixels; 2048 blocks (8/CU).
// ---------------------------------------------------------------------------
#define SPITCH 200   // shorts per pixel row (192 + 8 pad)
#define NPX 32       // pixels per block

__global__ __launch_bounds__(256) void k_dcn(
    const ushort* __restrict__ x_clh, const float* __restrict__ om,
    const float* __restrict__ b_off, const ushort* __restrict__ wdT,
    const ushort* __restrict__ zp16,
    float* __restrict__ out) {
  __shared__ ushort S[NPX * SPITCH];       // 12.8 KB
  __shared__ int   cy[9 * NPX], cx[9 * NPX];
  __shared__ float cwy[9 * NPX], cwx[9 * NPX], cm[9 * NPX];

  int tid = threadIdx.x;
  int wave = tid >> 6, lane = tid & 63;
  int quad = lane >> 4, col = lane & 15;
  int rr = lane >> 3, g = lane & 7;        // gather: row-in-group, ch-group
  int pg0 = blockIdx.x * NPX;
  int b = pg0 >> 14;
  int o_base = __builtin_amdgcn_readfirstlane(wave * 16);

  // ---- phase 0: coords once per (pixel, tap), lane = pixel ----
  for (int i = tid; i < 9 * NPX; i += 256) {
    int k = i >> 5, p = i & 31;
    int pg = pg0 + p;
    int hw = pg & 16383;
    int h = hw >> 7, w = hw & 127;
    float dy = om[(size_t)k * NPIX + pg] + b_off[k];
    float dx = om[(size_t)(9 + k) * NPIX + pg] + b_off[9 + k];
    float mz = om[(size_t)(18 + k) * NPIX + pg] + b_off[18 + k];
    float py = (float)(h + (k / 3) - 1) + dy;
    float px = (float)(w + (k % 3) - 1) + dx;
    float y0f = floorf(py), x0f = floorf(px);
    cy[i] = (int)y0f;
    cx[i] = (int)x0f;
    cwy[i] = py - y0f;
    cwx[i] = px - x0f;
    cm[i] = 1.f / (1.f + __expf(-mz));
  }

  f32x4 acc[2];
  acc[0] = (f32x4){0.f, 0.f, 0.f, 0.f};
  acc[1] = (f32x4){0.f, 0.f, 0.f, 0.f};

  const ushort* bp = x_clh + (size_t)b * HW * 64;

  for (int chunk = 0; chunk < 3; ++chunk) {
    __syncthreads();   // chunk 0: coords ready; later: S free for reuse
    // ---- phase 1: 96 rows; iteration `it` covers tap kk=it, px p=wave*8+rr
#pragma unroll
    for (int it = 0; it < 3; ++it) {
      int p = wave * 8 + rr;
      int idx = (chunk * 3 + it) * NPX + p;
      int y0 = cy[idx], x0 = cx[idx];
      float wy = cwy[idx], wx = cwx[idx], m = cm[idx];
      bool yok0 = (unsigned)y0 < 128u, yok1 = (unsigned)(y0 + 1) < 128u;
      bool xok0 = (unsigned)x0 < 128u, xok1 = (unsigned)(x0 + 1) < 128u;
      const ushort* r0 = bp + ((size_t)(int)((y0 << 7) + x0)) * 64 + g * 8;
      const ushort* r1 = r0 + (size_t)WW * 64;
      short8 s00 = *(const short8*)((yok0 && xok0) ? r0 : zp16);
      short8 s01 = *(const short8*)((yok0 && xok1) ? (r0 + 64) : zp16);
      short8 s10 = *(const short8*)((yok1 && xok0) ? r1 : zp16);
      short8 s11 = *(const short8*)((yok1 && xok1) ? (r1 + 64) : zp16);
      short8 outv;
#pragma unroll
      for (int j = 0; j < 8; ++j) {
        float v00 = bf2f((ushort)s00[j]), v01 = bf2f((ushort)s01[j]);
        float v10 = bf2f((ushort)s10[j]), v11 = bf2f((ushort)s11[j]);
        float top = v00 + (v01 - v00) * wx;
        float bot = v10 + (v11 - v10) * wx;
        float val = top + (bot - top) * wy;
        outv[j] = (short)f2bf(val * m);
      }
      *(short8*)(&S[p * SPITCH + it * 64 + g * 8]) = outv;
    }
    __syncthreads();
    // ---- phase 2: MFMA over this chunk's K=192 ----
    const ushort* wrow = wdT + (size_t)(o_base + col) * 576 + chunk * 192 + quad * 8;
    const ushort* srow = S + quad * 8;
#pragma unroll
    for (int ks = 0; ks < 6; ++ks) {
      short8 a = *(const short8*)(wrow + ks * 32);
#pragma unroll
      for (int nt = 0; nt < 2; ++nt) {
        short8 bf = *(const short8*)(srow + (nt * 16 + col) * SPITCH + ks * 32);
        acc[nt] = __builtin_amdgcn_mfma_f32_16x16x32_bf16(a, bf, acc[nt], 0, 0, 0);
      }
    }
  }

  // ---- epilogue: out[(b*64+o)*HW + hw0 + px] += D ----
  int hw0 = pg0 & 16383;
#pragma unroll
  for (int nt = 0; nt < 2; ++nt) {
#pragma unroll
    for (int r = 0; r < 4; ++r) {
      int o = o_base + quad * 4 + r;
      size_t idx = (size_t)(b * 64 + o) * HW + hw0 + nt * 16 + col;
      out[idx] += acc[nt][r];
    }
  }
}

// ---------------------------------------------------------------------------
// Workspace plan (float slots), all concurrent (~24 MB):
//   x_clh     ushort [0        .. 2097152)
//   inter_clh ushort [2097152  .. 4194304)
//   om        fp32   [4194304  .. 5963776)
//   wfb       ushort [5963776  .. 5982208)
//   wdT       ushort [5982208  .. 6000640)
//   w1gb/w1bb/w2gb/w2bb ushort 4 x 2048 float slots [6000640 .. 6008832)
//   zp        fp32   [6008832  .. 6008896)
// ---------------------------------------------------------------------------
extern "C" void kernel_launch(void* const* d_in, const int* in_sizes, int n_in,
                              void* d_out, int out_size, void* d_ws, size_t ws_size,
                              hipStream_t stream) {
  const float* x     = (const float*)d_in[0];
  const float* inter = (const float*)d_in[1];
  const float* w_off = (const float*)d_in[2];
  const float* b_off = (const float*)d_in[3];
  const float* w_dcn = (const float*)d_in[4];
  const float* wg1   = (const float*)d_in[5];
  const float* wg2   = (const float*)d_in[6];
  const float* wb1   = (const float*)d_in[7];
  const float* wb2   = (const float*)d_in[8];
  float* out = (float*)d_out;

  float* ws        = (float*)d_ws;
  ushort* x_clh    = (ushort*)ws;
  ushort* inter_clh= (ushort*)(ws + 2097152);
  float* om        = ws + 4194304;
  ushort* wfb      = (ushort*)(ws + 5963776);
  ushort* wdT      = (ushort*)(ws + 5982208);
  ushort* w1gb     = (ushort*)(ws + 6000640);
  ushort* w1bb     = (ushort*)(ws + 6002688);
  ushort* w2gb     = (ushort*)(ws + 6004736);
  ushort* w2bb     = (ushort*)(ws + 6006784);
  float* zp        = ws + 6008832;

  // Prep: channels-last bf16 inputs + all packed weights + zero page.
  k_transp<<<1024, 256, 0, stream>>>(x, inter, x_clh, inter_clh);
  k_wprep<<<352, 256, 0, stream>>>(w_off, w_dcn, wg1, wb1, wg2, wb2,
                                   wfb, wdT, w1gb, w1bb, w2gb, w2bb, zp);

  // SFT (MFMA, fused two stages): out = x*(1+gamma)+beta.
  k_sft<<<1024, 256, 0, stream>>>(x, inter_clh, w1gb, w1bb, w2gb, w2bb, out);

  // Offset conv (LDS-staged MFMA implicit GEMM, 2048 blocks).
  k_convm<<<2048, 256, 0, stream>>>(x_clh, inter_clh, wfb, om);

  // DCN (adds into out).
  k_dcn<<<2048, 256, 0, stream>>>(x_clh, om, b_off, wdT, (const ushort*)zp, out);
}

// Round 10
// 178.379 us; speedup vs baseline: 1.1584x; 1.0155x over previous
//
#include <hip/hip_runtime.h>
#include <hip/hip_bf16.h>
#include <math.h>

#define BB 4
#define CC 64
#define HH 128
#define WW 128
#define HW (HH*WW)          // 16384
#define NPIX (BB*HW)        // 65536

typedef __attribute__((ext_vector_type(8))) short short8;   // 8 bf16
typedef __attribute__((ext_vector_type(4))) float f32x4;

__device__ __forceinline__ float bf2f(ushort u) {
  union { unsigned u; float f; } v; v.u = ((unsigned)u) << 16; return v.f;
}
__device__ __forceinline__ ushort f2bf(float f) {
  __hip_bfloat16 h = __float2bfloat16(f); return *(ushort*)&h;
}

// ---------------------------------------------------------------------------
// Prep (merged): blk 0..1023   -> NCHW fp32 -> channels-last bf16 (x, inter)
//                blk 1024..1167 -> wfb[tap][m(32)][c(128)] (+ zero page)
//                blk 1168..1311 -> wdT bf16 [o][k*64+c]
//                blk 1312..1375 -> SFT weight matrices bf16 [o][c]
// ---------------------------------------------------------------------------
__global__ __launch_bounds__(256) void k_prep(
    const float* __restrict__ x, const float* __restrict__ inter,
    const float* __restrict__ w_off, const float* __restrict__ w_dcn,
    const float* __restrict__ wg1, const float* __restrict__ wb1,
    const float* __restrict__ wg2, const float* __restrict__ wb2,
    ushort* __restrict__ x_clh, ushort* __restrict__ inter_clh,
    ushort* __restrict__ wfb, ushort* __restrict__ wdT,
    ushort* __restrict__ w1gb, ushort* __restrict__ w1bb,
    ushort* __restrict__ w2gb, ushort* __restrict__ w2bb,
    float* __restrict__ zp) {
  __shared__ float tile[64 * 129];
  int blk = blockIdx.x;
  if (blk < 1024) {
    int sel = blk >> 9;
    int bh = blk & 511;
    int b = bh >> 7, h = bh & 127;
    const float* src = sel ? inter : x;
    ushort* dst = sel ? inter_clh : x_clh;
    const float* sp = src + (size_t)(b * 64) * HW + h * WW;
    for (int i = threadIdx.x; i < 64 * 128; i += 256) {
      int c = i >> 7, w = i & 127;
      tile[c * 129 + w] = sp[(size_t)c * HW + w];
    }
    __syncthreads();
    ushort* dp = dst + ((size_t)b * HW + h * WW) * 64;
    for (int i = threadIdx.x; i < 64 * 128; i += 256) {
      int w = i >> 6, c = i & 63;
      dp[w * 64 + c] = f2bf(tile[c * 129 + w]);
    }
  } else if (blk < 1168) {
    int i = (blk - 1024) * 256 + threadIdx.x;
    if (i < 64) zp[i] = 0.f;
    if (i < 9 * 32 * 128) {
      int tap = i >> 12, rem = i & 4095, m = rem >> 7, c = rem & 127;
      float v = (m < 27) ? w_off[(size_t)(m * 128 + c) * 9 + tap] : 0.f;
      wfb[i] = f2bf(v);
    }
  } else if (blk < 1312) {
    int i = (blk - 1168) * 256 + threadIdx.x;
    if (i < 64 * 64 * 9) {
      int o = i / 576, rem = i % 576, k = rem >> 6, c = rem & 63;
      wdT[i] = f2bf(w_dcn[(o * 64 + c) * 9 + k]);
    }
  } else {
    int i = (blk - 1312) * 256 + threadIdx.x;   // 0..16383
    int m = i >> 12, j = i & 4095;
    const float* src = (m == 0) ? wg1 : (m == 1) ? wb1 : (m == 2) ? wg2 : wb2;
    ushort* dst = (m == 0) ? w1gb : (m == 1) ? w1bb : (m == 2) ? w2gb : w2bb;
    dst[j] = f2bf(src[j]);
  }
}

// ---------------------------------------------------------------------------
// Offset conv: LDS-staged implicit GEMM (unchanged from R9 — works).
// Grid 2048 = (b, h, wq); block = 256 thr = 32 px; LDS 29.4 KB.
// ---------------------------------------------------------------------------
#define CPITCH 72   // shorts per (srcrow, px) channel row

__global__ __launch_bounds__(256) void k_convm(
    const ushort* __restrict__ x_clh, const ushort* __restrict__ inter_clh,
    const ushort* __restrict__ wfb, float* __restrict__ om) {
  __shared__ ushort S[6 * 34 * CPITCH];   // 29376 B
  int tid = threadIdx.x;
  int wave = tid >> 6, lane = tid & 63;
  int quad = lane >> 4, col = lane & 15;
  int blk = blockIdx.x;                 // b(4) x h(128) x wq(4)
  int b = blk >> 9, h = (blk >> 2) & 127, wq = blk & 3;
  int pt = wave >> 1, mt = wave & 1;

  // ---- staging: 204 entries (srcrow 0..5, pxl 0..33), 8 lanes/entry ----
  {
    int ch = (tid & 7) * 8;
    unsigned bbase = (unsigned)b * HW;
#pragma unroll
    for (int it = 0; it < 7; ++it) {
      int e = it * 32 + (tid >> 3);
      if (e < 204) {
        int srcrow = e / 34, pxl = e % 34;
        int src = srcrow / 3, row = srcrow % 3;
        int hs = h + row - 1;
        int ps = wq * 32 + pxl - 1;
        bool ok = ((unsigned)hs < 128u) && ((unsigned)ps < 128u);
        int hc = hs < 0 ? 0 : (hs > 127 ? 127 : hs);
        int pc = ps < 0 ? 0 : (ps > 127 ? 127 : ps);
        const ushort* sb = src ? inter_clh : x_clh;
        short8 v = *(const short8*)(sb + ((size_t)(bbase + (hc << 7) + pc)) * 64 + ch);
        short8 z = {0, 0, 0, 0, 0, 0, 0, 0};
        if (!ok) v = z;
        *(short8*)(&S[e * CPITCH + ch]) = v;
      }
    }
  }
  __syncthreads();

  // ---- compute: wave (pt, mt): 16 px x 16 out ----
  f32x4 accx = {0.f, 0.f, 0.f, 0.f}, acci = {0.f, 0.f, 0.f, 0.f};
  const ushort* wb0 = wfb + (size_t)(mt * 16 + col) * 128 + quad * 8;
  int pxb = pt * 16 + col;

#pragma unroll
  for (int ky = 0; ky < 3; ++ky) {
#pragma unroll
    for (int kx = 0; kx < 3; ++kx) {
      int tap = ky * 3 + kx;
      const ushort* wt = wb0 + (size_t)tap * 4096;
#pragma unroll
      for (int ks = 0; ks < 2; ++ks) {
        short8 a0 = *(const short8*)(wt + ks * 32);
        short8 b0 = *(const short8*)(&S[(ky * 34 + pxb + kx) * CPITCH + ks * 32 + quad * 8]);
        accx = __builtin_amdgcn_mfma_f32_16x16x32_bf16(a0, b0, accx, 0, 0, 0);
        short8 a1 = *(const short8*)(wt + 64 + ks * 32);
        short8 b1 = *(const short8*)(&S[((3 + ky) * 34 + pxb + kx) * CPITCH + ks * 32 + quad * 8]);
        acci = __builtin_amdgcn_mfma_f32_16x16x32_bf16(a1, b1, acci, 0, 0, 0);
      }
    }
  }

  int pg = b * HW + h * WW + wq * 32 + pt * 16 + col;
#pragma unroll
  for (int r = 0; r < 4; ++r) {
    int o = mt * 16 + quad * 4 + r;
    float v = accx[r] + acci[r];
    if (o < 27) om[(size_t)o * NPIX + pg] = v;
  }
}

// ---------------------------------------------------------------------------
// MEGA: fused SFT + DCN. Block = 256 thr (4 waves) = 32 px; 2048 blocks.
//  1) SFT stage A (MFMA, B-frags direct from inter_clh) -> lrelu -> Sg/Sb
//  2) SFT stage B (MFMA) -> gamma/beta kept in 16 VGPRs
//  3) coords phase (om+bias+sigmoid once per (px,tap)) -> LDS (aliases Sg/Sb)
//  4) 3 chunks: bilinear gather (16B/lane) -> S -> MFMA into dcn acc
//  5) epilogue: out = x + x*gamma + beta + dcn   (single pure write, no RMW)
// LDS: S 12.8 KB + union(Sg/Sb 9.2 KB | coords 5.76 KB) = 22.0 KB -> 7 blk/CU.
// ---------------------------------------------------------------------------
#define SPITCH 200   // shorts per pixel row (192 + 8 pad)
#define NPX 32       // pixels per block
#define FP32 72      // shorts per px row in Sg/Sb

__global__ __launch_bounds__(256) void k_mega(
    const float* __restrict__ x, const ushort* __restrict__ x_clh,
    const ushort* __restrict__ inter_clh, const float* __restrict__ om,
    const float* __restrict__ b_off, const ushort* __restrict__ wdT,
    const ushort* __restrict__ w1gb, const ushort* __restrict__ w1bb,
    const ushort* __restrict__ w2gb, const ushort* __restrict__ w2bb,
    const ushort* __restrict__ zp16, float* __restrict__ out) {
  __shared__ ushort S[NPX * SPITCH];            // 12800 B
  __shared__ __align__(16) char U[2 * NPX * FP32 * 2];  // 9216 B union
  ushort* Sg = (ushort*)U;                       // [32][72]
  ushort* Sb = Sg + NPX * FP32;
  int*   cy  = (int*)U;                          // 288 entries each
  int*   cx  = cy + 288;
  float* cwy = (float*)(cx + 288);
  float* cwx = cwy + 288;
  float* cm  = cwx + 288;                        // 5760 B total

  int tid = threadIdx.x;
  int wave = tid >> 6, lane = tid & 63;
  int quad = lane >> 4, col = lane & 15;
  int rr = lane >> 3, g = lane & 7;
  int pg0 = blockIdx.x * NPX;
  int b = pg0 >> 14, hw0 = pg0 & 16383;
  int o_base = __builtin_amdgcn_readfirstlane(wave * 16);

  // ---- SFT stage A: t1 = lrelu(W1 @ inter) ----
  f32x4 ag[2], ab[2];
#pragma unroll
  for (int nt = 0; nt < 2; ++nt) {
    ag[nt] = (f32x4){0.f, 0.f, 0.f, 0.f};
    ab[nt] = (f32x4){0.f, 0.f, 0.f, 0.f};
  }
#pragma unroll
  for (int ks = 0; ks < 2; ++ks) {
    short8 a_g = *(const short8*)(w1gb + (size_t)(o_base + col) * 64 + ks * 32 + quad * 8);
    short8 a_b = *(const short8*)(w1bb + (size_t)(o_base + col) * 64 + ks * 32 + quad * 8);
#pragma unroll
    for (int nt = 0; nt < 2; ++nt) {
      short8 bf = *(const short8*)(inter_clh + (size_t)(pg0 + nt * 16 + col) * 64 + ks * 32 + quad * 8);
      ag[nt] = __builtin_amdgcn_mfma_f32_16x16x32_bf16(a_g, bf, ag[nt], 0, 0, 0);
      ab[nt] = __builtin_amdgcn_mfma_f32_16x16x32_bf16(a_b, bf, ab[nt], 0, 0, 0);
    }
  }
#pragma unroll
  for (int nt = 0; nt < 2; ++nt) {
    int px = nt * 16 + col;
    ushort pkg[4], pkb[4];
#pragma unroll
    for (int r = 0; r < 4; ++r) {
      float vg = ag[nt][r]; vg = vg >= 0.f ? vg : 0.1f * vg;
      float vb = ab[nt][r]; vb = vb >= 0.f ? vb : 0.1f * vb;
      pkg[r] = f2bf(vg); pkb[r] = f2bf(vb);
    }
    *(uint2*)(&Sg[px * FP32 + o_base + quad * 4]) = *(uint2*)pkg;
    *(uint2*)(&Sb[px * FP32 + o_base + quad * 4]) = *(uint2*)pkb;
  }
  __syncthreads();

  // ---- SFT stage B: gamma/beta (kept in registers) ----
  f32x4 gg[2], gb[2];
#pragma unroll
  for (int nt = 0; nt < 2; ++nt) {
    gg[nt] = (f32x4){0.f, 0.f, 0.f, 0.f};
    gb[nt] = (f32x4){0.f, 0.f, 0.f, 0.f};
  }
#pragma unroll
  for (int ks = 0; ks < 2; ++ks) {
    short8 a_g = *(const short8*)(w2gb + (size_t)(o_base + col) * 64 + ks * 32 + quad * 8);
    short8 a_b = *(const short8*)(w2bb + (size_t)(o_base + col) * 64 + ks * 32 + quad * 8);
#pragma unroll
    for (int nt = 0; nt < 2; ++nt) {
      short8 bgf = *(const short8*)(Sg + (nt * 16 + col) * FP32 + ks * 32 + quad * 8);
      short8 bbf = *(const short8*)(Sb + (nt * 16 + col) * FP32 + ks * 32 + quad * 8);
      gg[nt] = __builtin_amdgcn_mfma_f32_16x16x32_bf16(a_g, bgf, gg[nt], 0, 0, 0);
      gb[nt] = __builtin_amdgcn_mfma_f32_16x16x32_bf16(a_b, bbf, gb[nt], 0, 0, 0);
    }
  }
  __syncthreads();   // Sg/Sb dead; U becomes coords

  // ---- coords phase: once per (pixel, tap), lane = pixel ----
  for (int i = tid; i < 9 * NPX; i += 256) {
    int k = i >> 5, p = i & 31;
    int pg = pg0 + p;
    int hw = pg & 16383;
    int h = hw >> 7, w = hw & 127;
    float dy = om[(size_t)k * NPIX + pg] + b_off[k];
    float dx = om[(size_t)(9 + k) * NPIX + pg] + b_off[9 + k];
    float mz = om[(size_t)(18 + k) * NPIX + pg] + b_off[18 + k];
    float py = (float)(h + (k / 3) - 1) + dy;
    float px = (float)(w + (k % 3) - 1) + dx;
    float y0f = floorf(py), x0f = floorf(px);
    cy[i] = (int)y0f;
    cx[i] = (int)x0f;
    cwy[i] = py - y0f;
    cwx[i] = px - x0f;
    cm[i] = 1.f / (1.f + __expf(-mz));
  }

  f32x4 acc[2];
  acc[0] = (f32x4){0.f, 0.f, 0.f, 0.f};
  acc[1] = (f32x4){0.f, 0.f, 0.f, 0.f};

  const ushort* bp = x_clh + (size_t)b * HW * 64;

  for (int chunk = 0; chunk < 3; ++chunk) {
    __syncthreads();   // chunk 0: coords ready; later: S free for reuse
#pragma unroll
    for (int it = 0; it < 3; ++it) {
      int p = wave * 8 + rr;
      int idx = (chunk * 3 + it) * NPX + p;
      int y0 = cy[idx], x0 = cx[idx];
      float wy = cwy[idx], wx = cwx[idx], m = cm[idx];
      bool yok0 = (unsigned)y0 < 128u, yok1 = (unsigned)(y0 + 1) < 128u;
      bool xok0 = (unsigned)x0 < 128u, xok1 = (unsigned)(x0 + 1) < 128u;
      const ushort* r0 = bp + ((size_t)(int)((y0 << 7) + x0)) * 64 + g * 8;
      const ushort* r1 = r0 + (size_t)WW * 64;
      short8 s00 = *(const short8*)((yok0 && xok0) ? r0 : zp16);
      short8 s01 = *(const short8*)((yok0 && xok1) ? (r0 + 64) : zp16);
      short8 s10 = *(const short8*)((yok1 && xok0) ? r1 : zp16);
      short8 s11 = *(const short8*)((yok1 && xok1) ? (r1 + 64) : zp16);
      short8 outv;
#pragma unroll
      for (int j = 0; j < 8; ++j) {
        float v00 = bf2f((ushort)s00[j]), v01 = bf2f((ushort)s01[j]);
        float v10 = bf2f((ushort)s10[j]), v11 = bf2f((ushort)s11[j]);
        float top = v00 + (v01 - v00) * wx;
        float bot = v10 + (v11 - v10) * wx;
        float val = top + (bot - top) * wy;
        outv[j] = (short)f2bf(val * m);
      }
      *(short8*)(&S[p * SPITCH + it * 64 + g * 8]) = outv;
    }
    __syncthreads();
    const ushort* wrow = wdT + (size_t)(o_base + col) * 576 + chunk * 192 + quad * 8;
    const ushort* srow = S + quad * 8;
#pragma unroll
    for (int ks = 0; ks < 6; ++ks) {
      short8 a = *(const short8*)(wrow + ks * 32);
#pragma unroll
      for (int nt = 0; nt < 2; ++nt) {
        short8 bf = *(const short8*)(srow + (nt * 16 + col) * SPITCH + ks * 32);
        acc[nt] = __builtin_amdgcn_mfma_f32_16x16x32_bf16(a, bf, acc[nt], 0, 0, 0);
      }
    }
  }

  // ---- epilogue: out = x + x*gamma + beta + dcn  (single write) ----
#pragma unroll
  for (int nt = 0; nt < 2; ++nt) {
#pragma unroll
    for (int r = 0; r < 4; ++r) {
      int o = o_base + quad * 4 + r;
      size_t idx = (size_t)(b * 64 + o) * HW + hw0 + nt * 16 + col;
      float xv = x[idx];
      out[idx] = xv + xv * gg[nt][r] + gb[nt][r] + acc[nt][r];
    }
  }
}

// ---------------------------------------------------------------------------
// Workspace plan (float slots), all concurrent (~24 MB):
//   x_clh     ushort [0        .. 2097152)
//   inter_clh ushort [2097152  .. 4194304)
//   om        fp32   [4194304  .. 5963776)
//   wfb       ushort [5963776  .. 5982208)
//   wdT       ushort [5982208  .. 6000640)
//   w1gb/w1bb/w2gb/w2bb ushort 4 x 2048 float slots [6000640 .. 6008832)
//   zp        fp32   [6008832  .. 6008896)
// ---------------------------------------------------------------------------
extern "C" void kernel_launch(void* const* d_in, const int* in_sizes, int n_in,
                              void* d_out, int out_size, void* d_ws, size_t ws_size,
                              hipStream_t stream) {
  const float* x     = (const float*)d_in[0];
  const float* inter = (const float*)d_in[1];
  const float* w_off = (const float*)d_in[2];
  const float* b_off = (const float*)d_in[3];
  const float* w_dcn = (const float*)d_in[4];
  const float* wg1   = (const float*)d_in[5];
  const float* wg2   = (const float*)d_in[6];
  const float* wb1   = (const float*)d_in[7];
  const float* wb2   = (const float*)d_in[8];
  float* out = (float*)d_out;

  float* ws        = (float*)d_ws;
  ushort* x_clh    = (ushort*)ws;
  ushort* inter_clh= (ushort*)(ws + 2097152);
  float* om        = ws + 4194304;
  ushort* wfb      = (ushort*)(ws + 5963776);
  ushort* wdT      = (ushort*)(ws + 5982208);
  ushort* w1gb     = (ushort*)(ws + 6000640);
  ushort* w1bb     = (ushort*)(ws + 6002688);
  ushort* w2gb     = (ushort*)(ws + 6004736);
  ushort* w2bb     = (ushort*)(ws + 6006784);
  float* zp        = ws + 6008832;

  // Prep: channels-last bf16 inputs + all packed weights + zero page.
  k_prep<<<1376, 256, 0, stream>>>(x, inter, w_off, w_dcn, wg1, wb1, wg2, wb2,
                                   x_clh, inter_clh, wfb, wdT,
                                   w1gb, w1bb, w2gb, w2bb, zp);

  // Offset conv (LDS-staged MFMA implicit GEMM).
  k_convm<<<2048, 256, 0, stream>>>(x_clh, inter_clh, wfb, om);

  // Fused SFT + DCN: out = x + dcn + x*gamma + beta.
  k_mega<<<2048, 256, 0, stream>>>(x, x_clh, inter_clh, om, b_off, wdT,
                                   w1gb, w1bb, w2gb, w2bb,
                                   (const ushort*)zp, out);
}

// Round 11
// 172.138 us; speedup vs baseline: 1.2004x; 1.0363x over previous
//
#include <hip/hip_runtime.h>
#include <hip/hip_bf16.h>
#include <math.h>

#define BB 4
#define CC 64
#define HH 128
#define WW 128
#define HW (HH*WW)          // 16384
#define NPIX (BB*HW)        // 65536

typedef __attribute__((ext_vector_type(8))) short short8;   // 8 bf16
typedef __attribute__((ext_vector_type(4))) float f32x4;

__device__ __forceinline__ float bf2f(ushort u) {
  union { unsigned u; float f; } v; v.u = ((unsigned)u) << 16; return v.f;
}
__device__ __forceinline__ ushort f2bf(float f) {
  __hip_bfloat16 h = __float2bfloat16(f); return *(ushort*)&h;
}

// ---------------------------------------------------------------------------
// Prep (merged): blk 0..1023   -> NCHW fp32 -> channels-last bf16 (x, inter)
//                blk 1024..1167 -> wfb[tap][m(32)][c(128)] (+ zero page)
//                blk 1168..1311 -> wdT bf16 [o][k*64+c]
//                blk 1312..1375 -> SFT weight matrices bf16 [o][c]
// ---------------------------------------------------------------------------
__global__ __launch_bounds__(256) void k_prep(
    const float* __restrict__ x, const float* __restrict__ inter,
    const float* __restrict__ w_off, const float* __restrict__ w_dcn,
    const float* __restrict__ wg1, const float* __restrict__ wb1,
    const float* __restrict__ wg2, const float* __restrict__ wb2,
    ushort* __restrict__ x_clh, ushort* __restrict__ inter_clh,
    ushort* __restrict__ wfb, ushort* __restrict__ wdT,
    ushort* __restrict__ w1gb, ushort* __restrict__ w1bb,
    ushort* __restrict__ w2gb, ushort* __restrict__ w2bb,
    float* __restrict__ zp) {
  __shared__ float tile[64 * 129];
  int blk = blockIdx.x;
  if (blk < 1024) {
    int sel = blk >> 9;
    int bh = blk & 511;
    int b = bh >> 7, h = bh & 127;
    const float* src = sel ? inter : x;
    ushort* dst = sel ? inter_clh : x_clh;
    const float* sp = src + (size_t)(b * 64) * HW + h * WW;
    for (int i = threadIdx.x; i < 64 * 128; i += 256) {
      int c = i >> 7, w = i & 127;
      tile[c * 129 + w] = sp[(size_t)c * HW + w];
    }
    __syncthreads();
    ushort* dp = dst + ((size_t)b * HW + h * WW) * 64;
    for (int i = threadIdx.x; i < 64 * 128; i += 256) {
      int w = i >> 6, c = i & 63;
      dp[w * 64 + c] = f2bf(tile[c * 129 + w]);
    }
  } else if (blk < 1168) {
    int i = (blk - 1024) * 256 + threadIdx.x;
    if (i < 64) zp[i] = 0.f;
    if (i < 9 * 32 * 128) {
      int tap = i >> 12, rem = i & 4095, m = rem >> 7, c = rem & 127;
      float v = (m < 27) ? w_off[(size_t)(m * 128 + c) * 9 + tap] : 0.f;
      wfb[i] = f2bf(v);
    }
  } else if (blk < 1312) {
    int i = (blk - 1168) * 256 + threadIdx.x;
    if (i < 64 * 64 * 9) {
      int o = i / 576, rem = i % 576, k = rem >> 6, c = rem & 63;
      wdT[i] = f2bf(w_dcn[(o * 64 + c) * 9 + k]);
    }
  } else {
    int i = (blk - 1312) * 256 + threadIdx.x;   // 0..16383
    int m = i >> 12, j = i & 4095;
    const float* src = (m == 0) ? wg1 : (m == 1) ? wb1 : (m == 2) ? wg2 : wb2;
    ushort* dst = (m == 0) ? w1gb : (m == 1) ? w1bb : (m == 2) ? w2gb : w2bb;
    dst[j] = f2bf(src[j]);
  }
}

// ---------------------------------------------------------------------------
// OMEGA: fully fused conv + SFT + DCN. Block = 256 thr (4 waves) = 32 px;
// 2048 blocks = (b, h, wq).
//  1) conv halo staging (2 src x 3 rows x 34 px, ch-pitch 72) -> BIGB
//  2) conv MFMAs (wave = (pt, mt), 16px x 16out) -> om_local LDS [27][33] f32
//     (om NEVER goes to global: killed 14 MB of traffic + a whole kernel)
//  3) SFT stage A (B-frags from inter_clh) -> lrelu -> Sg/Sb (alias BIGB+12800)
//  4) SFT stage B -> gamma/beta in 16 VGPRs
//  5) coords from om_local (+bias+sigmoid once per (px,tap)) -> alias BIGB+12800
//  6) 3 chunks: bilinear gather (16B/lane) -> S (alias BIGB+0) -> MFMA
//  7) epilogue: out = x + x*gamma + beta + dcn (single pure write; x prefetched)
// LDS: BIGB 29376 + om_local 3696 = 33072 B -> 4 blocks/CU = 16 waves/CU.
// ---------------------------------------------------------------------------
#define CPITCH 72    // shorts per (srcrow, px) channel row in conv halo
#define SPITCH 200   // shorts per pixel row in gather buffer S
#define NPX 32       // pixels per block
#define FPX 72       // shorts per px row in Sg/Sb

__global__ __launch_bounds__(256) void k_omega(
    const float* __restrict__ x, const ushort* __restrict__ x_clh,
    const ushort* __restrict__ inter_clh,
    const float* __restrict__ b_off, const ushort* __restrict__ wfb,
    const ushort* __restrict__ wdT,
    const ushort* __restrict__ w1gb, const ushort* __restrict__ w1bb,
    const ushort* __restrict__ w2gb, const ushort* __restrict__ w2bb,
    const ushort* __restrict__ zp16, float* __restrict__ out) {
  __shared__ __align__(16) ushort BIGB[6 * 34 * CPITCH];   // 29376 B
  __shared__ float oml[28 * 33];                           // 3696 B
  // Aliases (serial reuse, barrier-separated):
  ushort* S  = BIGB;                      // 32*200 shorts = 12800 B (phases 1,6)
  ushort* Sg = BIGB + 6400;               // 32*72 shorts (phases 3-4)
  ushort* Sb = Sg + NPX * FPX;
  int*   cy  = (int*)(BIGB + 6400);       // coords (phases 5-6): 288 each
  int*   cx  = cy + 288;
  float* cwy = (float*)(cx + 288);
  float* cwx = cwy + 288;
  float* cm  = cwx + 288;                 // 5760 B total

  int tid = threadIdx.x;
  int wave = tid >> 6, lane = tid & 63;
  int quad = lane >> 4, col = lane & 15;
  int rr = lane >> 3, g = lane & 7;
  int pg0 = blockIdx.x * NPX;
  int b = pg0 >> 14, hw0 = pg0 & 16383;
  int h = hw0 >> 7, w0 = hw0 & 127;
  int pt = wave >> 1, mt = wave & 1;
  int o_base = __builtin_amdgcn_readfirstlane(wave * 16);

  // ---- phase 1: conv halo staging ----
  {
    int ch = (tid & 7) * 8;
    unsigned bbase = (unsigned)b * HW;
#pragma unroll
    for (int it = 0; it < 7; ++it) {
      int e = it * 32 + (tid >> 3);
      if (e < 204) {
        int srcrow = e / 34, pxl = e % 34;
        int src = srcrow / 3, row = srcrow % 3;
        int hs = h + row - 1;
        int ps = w0 + pxl - 1;
        bool ok = ((unsigned)hs < 128u) && ((unsigned)ps < 128u);
        int hc = hs < 0 ? 0 : (hs > 127 ? 127 : hs);
        int pc = ps < 0 ? 0 : (ps > 127 ? 127 : ps);
        const ushort* sb = src ? inter_clh : x_clh;
        short8 v = *(const short8*)(sb + ((size_t)(bbase + (hc << 7) + pc)) * 64 + ch);
        short8 z = {0, 0, 0, 0, 0, 0, 0, 0};
        if (!ok) v = z;
        *(short8*)(&BIGB[e * CPITCH + ch]) = v;
      }
    }
  }
  __syncthreads();

  // ---- phase 2: conv MFMAs -> om_local ----
  {
    f32x4 accx = {0.f, 0.f, 0.f, 0.f}, acci = {0.f, 0.f, 0.f, 0.f};
    const ushort* wb0 = wfb + (size_t)(mt * 16 + col) * 128 + quad * 8;
    int pxb = pt * 16 + col;
#pragma unroll
    for (int ky = 0; ky < 3; ++ky) {
#pragma unroll
      for (int kx = 0; kx < 3; ++kx) {
        int tap = ky * 3 + kx;
        const ushort* wt = wb0 + (size_t)tap * 4096;
#pragma unroll
        for (int ks = 0; ks < 2; ++ks) {
          short8 a0 = *(const short8*)(wt + ks * 32);
          short8 b0 = *(const short8*)(&BIGB[(ky * 34 + pxb + kx) * CPITCH + ks * 32 + quad * 8]);
          accx = __builtin_amdgcn_mfma_f32_16x16x32_bf16(a0, b0, accx, 0, 0, 0);
          short8 a1 = *(const short8*)(wt + 64 + ks * 32);
          short8 b1 = *(const short8*)(&BIGB[((3 + ky) * 34 + pxb + kx) * CPITCH + ks * 32 + quad * 8]);
          acci = __builtin_amdgcn_mfma_f32_16x16x32_bf16(a1, b1, acci, 0, 0, 0);
        }
      }
    }
#pragma unroll
    for (int r = 0; r < 4; ++r) {
      int o = mt * 16 + quad * 4 + r;
      if (o < 27) oml[o * 33 + pt * 16 + col] = accx[r] + acci[r];
    }
  }
  __syncthreads();   // om_local complete; BIGB free

  // ---- phase 3: SFT stage A -> Sg/Sb ----
  f32x4 ag[2], ab[2];
#pragma unroll
  for (int nt = 0; nt < 2; ++nt) {
    ag[nt] = (f32x4){0.f, 0.f, 0.f, 0.f};
    ab[nt] = (f32x4){0.f, 0.f, 0.f, 0.f};
  }
#pragma unroll
  for (int ks = 0; ks < 2; ++ks) {
    short8 a_g = *(const short8*)(w1gb + (size_t)(o_base + col) * 64 + ks * 32 + quad * 8);
    short8 a_b = *(const short8*)(w1bb + (size_t)(o_base + col) * 64 + ks * 32 + quad * 8);
#pragma unroll
    for (int nt = 0; nt < 2; ++nt) {
      short8 bf = *(const short8*)(inter_clh + (size_t)(pg0 + nt * 16 + col) * 64 + ks * 32 + quad * 8);
      ag[nt] = __builtin_amdgcn_mfma_f32_16x16x32_bf16(a_g, bf, ag[nt], 0, 0, 0);
      ab[nt] = __builtin_amdgcn_mfma_f32_16x16x32_bf16(a_b, bf, ab[nt], 0, 0, 0);
    }
  }
#pragma unroll
  for (int nt = 0; nt < 2; ++nt) {
    int px = nt * 16 + col;
    ushort pkg[4], pkb[4];
#pragma unroll
    for (int r = 0; r < 4; ++r) {
      float vg = ag[nt][r]; vg = vg >= 0.f ? vg : 0.1f * vg;
      float vb = ab[nt][r]; vb = vb >= 0.f ? vb : 0.1f * vb;
      pkg[r] = f2bf(vg); pkb[r] = f2bf(vb);
    }
    *(uint2*)(&Sg[px * FPX + o_base + quad * 4]) = *(uint2*)pkg;
    *(uint2*)(&Sb[px * FPX + o_base + quad * 4]) = *(uint2*)pkb;
  }
  __syncthreads();

  // ---- phase 4: SFT stage B -> gamma/beta in registers ----
  f32x4 gg[2], gb[2];
#pragma unroll
  for (int nt = 0; nt < 2; ++nt) {
    gg[nt] = (f32x4){0.f, 0.f, 0.f, 0.f};
    gb[nt] = (f32x4){0.f, 0.f, 0.f, 0.f};
  }
#pragma unroll
  for (int ks = 0; ks < 2; ++ks) {
    short8 a_g = *(const short8*)(w2gb + (size_t)(o_base + col) * 64 + ks * 32 + quad * 8);
    short8 a_b = *(const short8*)(w2bb + (size_t)(o_base + col) * 64 + ks * 32 + quad * 8);
#pragma unroll
    for (int nt = 0; nt < 2; ++nt) {
      short8 bgf = *(const short8*)(Sg + (nt * 16 + col) * FPX + ks * 32 + quad * 8);
      short8 bbf = *(const short8*)(Sb + (nt * 16 + col) * FPX + ks * 32 + quad * 8);
      gg[nt] = __builtin_amdgcn_mfma_f32_16x16x32_bf16(a_g, bgf, gg[nt], 0, 0, 0);
      gb[nt] = __builtin_amdgcn_mfma_f32_16x16x32_bf16(a_b, bbf, gb[nt], 0, 0, 0);
    }
  }
  // Prefetch epilogue x values (independent of everything below).
  float xv[2][4];
#pragma unroll
  for (int nt = 0; nt < 2; ++nt)
#pragma unroll
    for (int r = 0; r < 4; ++r) {
      int o = o_base + quad * 4 + r;
      xv[nt][r] = x[(size_t)(b * 64 + o) * HW + hw0 + nt * 16 + col];
    }
  __syncthreads();   // Sg/Sb dead; region becomes coords

  // ---- phase 5: coords once per (pixel, tap) from om_local ----
  for (int i = tid; i < 9 * NPX; i += 256) {
    int k = i >> 5, p = i & 31;
    float dy = oml[k * 33 + p] + b_off[k];
    float dx = oml[(9 + k) * 33 + p] + b_off[9 + k];
    float mz = oml[(18 + k) * 33 + p] + b_off[18 + k];
    float py = (float)(h + (k / 3) - 1) + dy;
    float px = (float)(w0 + p + (k % 3) - 1) + dx;
    float y0f = floorf(py), x0f = floorf(px);
    cy[i] = (int)y0f;
    cx[i] = (int)x0f;
    cwy[i] = py - y0f;
    cwx[i] = px - x0f;
    cm[i] = 1.f / (1.f + __expf(-mz));
  }

  f32x4 acc[2];
  acc[0] = (f32x4){0.f, 0.f, 0.f, 0.f};
  acc[1] = (f32x4){0.f, 0.f, 0.f, 0.f};

  const ushort* bp = x_clh + (size_t)b * HW * 64;

  // ---- phase 6: gather + MFMA chunks ----
  for (int chunk = 0; chunk < 3; ++chunk) {
    __syncthreads();   // chunk 0: coords ready; later: S free for reuse
#pragma unroll
    for (int it = 0; it < 3; ++it) {
      int p = wave * 8 + rr;
      int idx = (chunk * 3 + it) * NPX + p;
      int y0 = cy[idx], x0 = cx[idx];
      float wy = cwy[idx], wx = cwx[idx], m = cm[idx];
      bool yok0 = (unsigned)y0 < 128u, yok1 = (unsigned)(y0 + 1) < 128u;
      bool xok0 = (unsigned)x0 < 128u, xok1 = (unsigned)(x0 + 1) < 128u;
      const ushort* r0 = bp + ((size_t)(int)((y0 << 7) + x0)) * 64 + g * 8;
      const ushort* r1 = r0 + (size_t)WW * 64;
      short8 s00 = *(const short8*)((yok0 && xok0) ? r0 : zp16);
      short8 s01 = *(const short8*)((yok0 && xok1) ? (r0 + 64) : zp16);
      short8 s10 = *(const short8*)((yok1 && xok0) ? r1 : zp16);
      short8 s11 = *(const short8*)((yok1 && xok1) ? (r1 + 64) : zp16);
      short8 outv;
#pragma unroll
      for (int j = 0; j < 8; ++j) {
        float v00 = bf2f((ushort)s00[j]), v01 = bf2f((ushort)s01[j]);
        float v10 = bf2f((ushort)s10[j]), v11 = bf2f((ushort)s11[j]);
        float top = v00 + (v01 - v00) * wx;
        float bot = v10 + (v11 - v10) * wx;
        float val = top + (bot - top) * wy;
        outv[j] = (short)f2bf(val * m);
      }
      *(short8*)(&S[p * SPITCH + it * 64 + g * 8]) = outv;
    }
    __syncthreads();
    const ushort* wrow = wdT + (size_t)(o_base + col) * 576 + chunk * 192 + quad * 8;
    const ushort* srow = S + quad * 8;
#pragma unroll
    for (int ks = 0; ks < 6; ++ks) {
      short8 a = *(const short8*)(wrow + ks * 32);
#pragma unroll
      for (int nt = 0; nt < 2; ++nt) {
        short8 bf = *(const short8*)(srow + (nt * 16 + col) * SPITCH + ks * 32);
        acc[nt] = __builtin_amdgcn_mfma_f32_16x16x32_bf16(a, bf, acc[nt], 0, 0, 0);
      }
    }
  }

  // ---- phase 7: epilogue: out = x + x*gamma + beta + dcn (single write) ----
#pragma unroll
  for (int nt = 0; nt < 2; ++nt) {
#pragma unroll
    for (int r = 0; r < 4; ++r) {
      int o = o_base + quad * 4 + r;
      size_t idx = (size_t)(b * 64 + o) * HW + hw0 + nt * 16 + col;
      out[idx] = xv[nt][r] + xv[nt][r] * gg[nt][r] + gb[nt][r] + acc[nt][r];
    }
  }
}

// ---------------------------------------------------------------------------
// Workspace plan (float slots), all concurrent (~17 MB; om eliminated):
//   x_clh     ushort [0        .. 2097152)
//   inter_clh ushort [2097152  .. 4194304)
//   wfb       ushort [5963776  .. 5982208)
//   wdT       ushort [5982208  .. 6000640)
//   w1gb/w1bb/w2gb/w2bb ushort 4 x 2048 float slots [6000640 .. 6008832)
//   zp        fp32   [6008832  .. 6008896)
// ---------------------------------------------------------------------------
extern "C" void kernel_launch(void* const* d_in, const int* in_sizes, int n_in,
                              void* d_out, int out_size, void* d_ws, size_t ws_size,
                              hipStream_t stream) {
  const float* x     = (const float*)d_in[0];
  const float* inter = (const float*)d_in[1];
  const float* w_off = (const float*)d_in[2];
  const float* b_off = (const float*)d_in[3];
  const float* w_dcn = (const float*)d_in[4];
  const float* wg1   = (const float*)d_in[5];
  const float* wg2   = (const float*)d_in[6];
  const float* wb1   = (const float*)d_in[7];
  const float* wb2   = (const float*)d_in[8];
  float* out = (float*)d_out;

  float* ws        = (float*)d_ws;
  ushort* x_clh    = (ushort*)ws;
  ushort* inter_clh= (ushort*)(ws + 2097152);
  ushort* wfb      = (ushort*)(ws + 5963776);
  ushort* wdT      = (ushort*)(ws + 5982208);
  ushort* w1gb     = (ushort*)(ws + 6000640);
  ushort* w1bb     = (ushort*)(ws + 6002688);
  ushort* w2gb     = (ushort*)(ws + 6004736);
  ushort* w2bb     = (ushort*)(ws + 6006784);
  float* zp        = ws + 6008832;

  // Prep: channels-last bf16 inputs + all packed weights + zero page.
  k_prep<<<1376, 256, 0, stream>>>(x, inter, w_off, w_dcn, wg1, wb1, wg2, wb2,
                                   x_clh, inter_clh, wfb, wdT,
                                   w1gb, w1bb, w2gb, w2bb, zp);

  // Fully fused conv + SFT + DCN.
  k_omega<<<2048, 256, 0, stream>>>(x, x_clh, inter_clh, b_off, wfb, wdT,
                                    w1gb, w1bb, w2gb, w2bb,
                                    (const ushort*)zp, out);
}